// Round 5
// baseline (9627.370 us; speedup 1.0000x reference)
//
#include <hip/hip_runtime.h>
#include <math.h>

#define B_ 16
#define T_ 512
#define E_ 2048
#define H_ 1024
#define D_ 128
#define G_SCAN 64            // persistent workgroups for the scan (1 per CU, 64 <= 256 CUs)
#define ROWS_PER_WG 16       // H_/G_SCAN

typedef unsigned long long u64;

// ---------------- ws layout ----------------
// [4096,  20480) : hbuf2[2][H_] (u64 {tag,valbits}) -- zeroed each launch (h0=0, tag=0)
// [32768, 98304) : hs[B_][H_] (float)
// [131072,+32MB) : xW[B_*T_][H_] (float)

// ---- device-coherent 8B store (sc0 sc1: bypass non-coherent caches to coherence point) ----
__device__ __forceinline__ void store_u64_cohere(u64* p, u64 v) {
    asm volatile("global_store_dwordx2 %0, %1, off sc0 sc1"
                 :: "v"(p), "v"(v) : "memory");
}
// ---- issue 4 coherent 8B loads WITHOUT waiting (stream building block) ----
__device__ __forceinline__ void issue4(const u64* p0, const u64* p1,
                                       const u64* p2, const u64* p3,
                                       u64& a, u64& b, u64& c, u64& d) {
    asm volatile("global_load_dwordx2 %0, %4, off sc0 sc1\n\t"
                 "global_load_dwordx2 %1, %5, off sc0 sc1\n\t"
                 "global_load_dwordx2 %2, %6, off sc0 sc1\n\t"
                 "global_load_dwordx2 %3, %7, off sc0 sc1"
                 : "=&v"(a), "=&v"(b), "=&v"(c), "=&v"(d)
                 : "v"(p0), "v"(p1), "v"(p2), "v"(p3)
                 : "memory");
}
// ---- waits with explicit register dependence (so C-level reads can't move above) ----
__device__ __forceinline__ void wait_vm4(u64& a, u64& b, u64& c, u64& d) {
    asm volatile("s_waitcnt vmcnt(4)" : "+v"(a), "+v"(b), "+v"(c), "+v"(d) :: "memory");
}
__device__ __forceinline__ void wait_vm0(u64& a, u64& b, u64& c, u64& d) {
    asm volatile("s_waitcnt vmcnt(0)" : "+v"(a), "+v"(b), "+v"(c), "+v"(d) :: "memory");
}

// DPP butterfly add over a 16-lane row (VALU-rate, no LDS pipe).
template <int CTRL>
__device__ __forceinline__ float dpp_xadd(float v) {
    int vi = __float_as_int(v);
    int t  = __builtin_amdgcn_update_dpp(vi, vi, CTRL, 0xF, 0xF, true);
    return v + __int_as_float(t);
}

// fast tanh via v_exp_f32: tanh(x) = sign(x) * (1-e^{-2|x|})/(1+e^{-2|x|}); |err| ~1e-6
__device__ __forceinline__ float fast_tanh(float x) {
    float ax = fabsf(x);
    float e  = __expf(-2.0f * ax);
    float r  = __fdividef(1.0f - e, 1.0f + e);
    return copysignf(r, x);
}

// ================= Kernel 1: xW = x @ W_ih^T + (b_ih + b_hh) =================
__global__ __launch_bounds__(256) void gemm_xw(
    const float* __restrict__ x, const float* __restrict__ Wih,
    const float* __restrict__ bih, const float* __restrict__ bhh,
    float* __restrict__ xW)
{
    __shared__ float As[64][17];
    __shared__ float Bs[64][17];
    const int tid = threadIdx.x;
    const int bx = blockIdx.x;
    const int by = blockIdx.y;
    const int tx = tid & 15;
    const int ty = tid >> 4;
    const int lrow = tid >> 2;
    const int lcol = (tid & 3) * 4;

    const float* Ag = x   + (size_t)(by * 64 + lrow) * E_ + lcol;
    const float* Bg = Wih + (size_t)(bx * 64 + lrow) * E_ + lcol;

    float acc[4][4] = {};
    for (int kt = 0; kt < E_; kt += 16) {
        float4 av = *(const float4*)(Ag + kt);
        float4 bv = *(const float4*)(Bg + kt);
        As[lrow][lcol + 0] = av.x; As[lrow][lcol + 1] = av.y;
        As[lrow][lcol + 2] = av.z; As[lrow][lcol + 3] = av.w;
        Bs[lrow][lcol + 0] = bv.x; Bs[lrow][lcol + 1] = bv.y;
        Bs[lrow][lcol + 2] = bv.z; Bs[lrow][lcol + 3] = bv.w;
        __syncthreads();
#pragma unroll
        for (int kk = 0; kk < 16; ++kk) {
            float a0 = As[ty * 4 + 0][kk], a1 = As[ty * 4 + 1][kk];
            float a2 = As[ty * 4 + 2][kk], a3 = As[ty * 4 + 3][kk];
            float b0 = Bs[tx * 4 + 0][kk], b1 = Bs[tx * 4 + 1][kk];
            float b2 = Bs[tx * 4 + 2][kk], b3 = Bs[tx * 4 + 3][kk];
            acc[0][0] += a0 * b0; acc[0][1] += a0 * b1; acc[0][2] += a0 * b2; acc[0][3] += a0 * b3;
            acc[1][0] += a1 * b0; acc[1][1] += a1 * b1; acc[1][2] += a1 * b2; acc[1][3] += a1 * b3;
            acc[2][0] += a2 * b0; acc[2][1] += a2 * b1; acc[2][2] += a2 * b2; acc[2][3] += a2 * b3;
            acc[3][0] += a3 * b0; acc[3][1] += a3 * b1; acc[3][2] += a3 * b2; acc[3][3] += a3 * b3;
        }
        __syncthreads();
    }
#pragma unroll
    for (int i = 0; i < 4; ++i) {
        const int m = by * 64 + ty * 4 + i;
#pragma unroll
        for (int j = 0; j < 4; ++j) {
            const int n = bx * 64 + tx * 4 + j;
            xW[(size_t)m * H_ + n] = acc[i][j] + bih[n] + bhh[n];
        }
    }
}

// ================= Kernel 2: persistent sequential RNN scan =================
// Tagged-data protocol (no flags, no fences): slot i of buffer s&1 must carry tag s.
// Thread tid owns slots {tid, tid+256, tid+512, tid+768}.
// TWO interleaved poll streams (A/B, 8 loads in flight, vmcnt(4) retires one stream):
// sampling period ~RTT/2 instead of RTT. Loop exit is wave-uniform (__all), so no
// divergent re-issue; the dead stream is drained (vmcnt(0)) before its regs can die.
// LDS double-buffered, ONE barrier per step (safety argued in round-4 comment).
__global__ __launch_bounds__(256, 1) void rnn_scan(
    const float* __restrict__ Whh, const float* __restrict__ xW,
    const int* __restrict__ lengths,
    u64* __restrict__ hbuf2,   // [2][H_] {tag<<32 | value_bits}
    float* __restrict__ hs)    // [B_][H_]
{
    __shared__ float hsh2[2][16 * 68];
    const int tid = threadIdx.x;
    const int wg  = blockIdx.x;
    const int r   = tid >> 4;     // 0..15
    const int sub = tid & 15;     // 0..15
    const int row = wg * ROWS_PER_WG + r;

    float wreg[64];
#pragma unroll
    for (int j = 0; j < 64; ++j)
        wreg[j] = Whh[(size_t)row * H_ + sub + 16 * j];

    int s = 0, cur = 0;
    for (int b = 0; b < B_; ++b) {
        const int len = lengths[b];
        for (int t = 0; t < len; ++t) {
            // prefetch this step's xW value early (drains under the first poll wait)
            float xw = xW[(size_t)(b * T_ + t) * H_ + row];

            const u64* bin = hbuf2 + (size_t)(s & 1) * H_;
            const u64 *q0 = bin + tid, *q1 = bin + tid + 256,
                      *q2 = bin + tid + 512, *q3 = bin + tid + 768;
            const unsigned want = (unsigned)s;

            u64 A0, A1, A2, A3, B0, B1, B2, B3;
            u64 r0, r1, r2, r3;
            issue4(q0, q1, q2, q3, A0, A1, A2, A3);
            issue4(q0, q1, q2, q3, B0, B1, B2, B3);
            for (;;) {
                wait_vm4(A0, A1, A2, A3);          // stream A retired (B in flight)
                bool okA = (((unsigned)(A0 >> 32)) == want) & (((unsigned)(A1 >> 32)) == want) &
                           (((unsigned)(A2 >> 32)) == want) & (((unsigned)(A3 >> 32)) == want);
                if (__all(okA)) {
                    wait_vm0(B0, B1, B2, B3);      // drain dead stream before regs die
                    r0 = A0; r1 = A1; r2 = A2; r3 = A3;
                    break;
                }
                issue4(q0, q1, q2, q3, A0, A1, A2, A3);
                wait_vm4(B0, B1, B2, B3);          // stream B retired (A in flight)
                bool okB = (((unsigned)(B0 >> 32)) == want) & (((unsigned)(B1 >> 32)) == want) &
                           (((unsigned)(B2 >> 32)) == want) & (((unsigned)(B3 >> 32)) == want);
                if (__all(okB)) {
                    wait_vm0(A0, A1, A2, A3);
                    r0 = B0; r1 = B1; r2 = B2; r3 = B3;
                    break;
                }
                issue4(q0, q1, q2, q3, B0, B1, B2, B3);
            }

            // stage into current LDS buffer: perm(c)=sub*68 + r + 16k (2-way banks = free)
            float* wr = &hsh2[cur][sub * 68 + r];
            wr[0]  = __uint_as_float((unsigned)r0);
            wr[16] = __uint_as_float((unsigned)r1);
            wr[32] = __uint_as_float((unsigned)r2);
            wr[48] = __uint_as_float((unsigned)r3);
            __syncthreads();   // the ONLY barrier this step

            // ---- compute: 16x float4 LDS reads, 64 FMA in 4 independent chains
            const float* hrow = &hsh2[cur][sub * 68];
            float p0 = 0.f, p1 = 0.f, p2 = 0.f, p3 = 0.f;
#pragma unroll
            for (int m = 0; m < 16; ++m) {
                float4 hv = *(const float4*)(hrow + 4 * m);
                p0 += wreg[4 * m + 0] * hv.x;
                p1 += wreg[4 * m + 1] * hv.y;
                p2 += wreg[4 * m + 2] * hv.z;
                p3 += wreg[4 * m + 3] * hv.w;
            }
            float p = (p0 + p1) + (p2 + p3);
            // DPP butterfly over the 16-lane group (VALU-rate; no LDS pipe)
            p = dpp_xadd<0xB1>(p);    // quad_perm [1,0,3,2]  (xor 1)
            p = dpp_xadd<0x4E>(p);    // quad_perm [2,3,0,1]  (xor 2)
            p = dpp_xadd<0x141>(p);   // row_half_mirror
            p = dpp_xadd<0x140>(p);   // row_mirror

            float v = fast_tanh(xw + p);
            // ---- produce: single tagged 8B device-coherent store (lane sub==0 per row)
            if (sub == 0) {
                u64 pk = ((u64)(unsigned)(s + 1) << 32) | (u64)__float_as_uint(v);
                store_u64_cohere(hbuf2 + (size_t)((s + 1) & 1) * H_ + row, pk);
                if (t == len - 1) hs[(size_t)b * H_ + row] = v;  // final h of this row
            }
            cur ^= 1;
            ++s;
        }
    }
}

// ================= Kernel 3: out = hs @ W_l1^T + b_l1  (16x128) =================
__global__ __launch_bounds__(128) void out_gemm(
    const float* __restrict__ hs, const float* __restrict__ Wl1,
    const float* __restrict__ bl1, float* __restrict__ out)
{
    __shared__ float hshared[H_];
    const int b = blockIdx.x;
    const int d = threadIdx.x;
    for (int i = d; i < H_ / 4; i += 128)
        ((float4*)hshared)[i] = ((const float4*)(hs + (size_t)b * H_))[i];
    __syncthreads();
    float acc = 0.f;
    const float* wrow = Wl1 + (size_t)d * H_;
    for (int h = 0; h < H_; h += 4) {
        float4 w = *(const float4*)(wrow + h);
        acc += w.x * hshared[h] + w.y * hshared[h + 1]
             + w.z * hshared[h + 2] + w.w * hshared[h + 3];
    }
    out[b * D_ + d] = acc + bl1[d];
}

extern "C" void kernel_launch(void* const* d_in, const int* in_sizes, int n_in,
                              void* d_out, int out_size, void* d_ws, size_t ws_size,
                              hipStream_t stream) {
    const float* x       = (const float*)d_in[0];
    const int*   lengths = (const int*)  d_in[1];
    const float* Wih     = (const float*)d_in[2];
    const float* Whh     = (const float*)d_in[3];
    const float* bih     = (const float*)d_in[4];
    const float* bhh     = (const float*)d_in[5];
    const float* Wl1     = (const float*)d_in[6];
    const float* bl1     = (const float*)d_in[7];
    float* out = (float*)d_out;

    char* ws = (char*)d_ws;
    u64*   hbuf2 = (u64*)(ws + 4096);     // 16 KB
    float* hs  = (float*)(ws + 32768);    // 64 KB
    float* xW  = (float*)(ws + 131072);   // 32 MB

    // zero hbuf2 (h0 = 0.0f with tag 0); ws is re-poisoned 0xAA before every launch
    hipMemsetAsync(ws, 0, 32768, stream);

    dim3 g1(H_ / 64, (B_ * T_) / 64);   // (16, 128)
    gemm_xw<<<g1, 256, 0, stream>>>(x, Wih, bih, bhh, xW);

    rnn_scan<<<G_SCAN, 256, 0, stream>>>(Whh, xW, lengths, hbuf2, hs);

    out_gemm<<<B_, D_, 0, stream>>>(hs, Wl1, bl1, out);
}

// Round 6
// 9226.240 us; speedup vs baseline: 1.0435x; 1.0435x over previous
//
#include <hip/hip_runtime.h>
#include <math.h>

#define B_ 16
#define T_ 512
#define E_ 2048
#define H_ 1024
#define D_ 128
#define G_SCAN 64            // persistent workgroups for the scan (1 per CU, 64 <= 256 CUs)
#define ROWS_PER_WG 16       // H_/G_SCAN

typedef unsigned long long u64;

// ---------------- ws layout ----------------
// [4096,  20480) : hbuf2[2][H_] (u64 {tag,valbits}) -- zeroed each launch (h0=0, tag=0)
// [32768, 98304) : hs[B_][H_] (float)
// [131072,+32MB) : xW[B_*T_][H_] (float)

// ---- device-coherent 8B store (sc0 sc1: bypass non-coherent caches to coherence point) ----
__device__ __forceinline__ void store_u64_cohere(u64* p, u64 v) {
    asm volatile("global_store_dwordx2 %0, %1, off sc0 sc1"
                 :: "v"(p), "v"(v) : "memory");
}

// ---- 16 coherent 8B loads (slots lane+64k, k=0..15) issued back-to-back, ONE waitcnt.
// p1 = p0 + 512B*8 so all immediate offsets fit the 13-bit signed field.
__device__ __forceinline__ void poll16(const u64* p0, const u64* p1, u64* V) {
    asm volatile(
        "global_load_dwordx2 %0,  %16, off sc0 sc1\n\t"
        "global_load_dwordx2 %1,  %16, off offset:512  sc0 sc1\n\t"
        "global_load_dwordx2 %2,  %16, off offset:1024 sc0 sc1\n\t"
        "global_load_dwordx2 %3,  %16, off offset:1536 sc0 sc1\n\t"
        "global_load_dwordx2 %4,  %16, off offset:2048 sc0 sc1\n\t"
        "global_load_dwordx2 %5,  %16, off offset:2560 sc0 sc1\n\t"
        "global_load_dwordx2 %6,  %16, off offset:3072 sc0 sc1\n\t"
        "global_load_dwordx2 %7,  %16, off offset:3584 sc0 sc1\n\t"
        "global_load_dwordx2 %8,  %17, off sc0 sc1\n\t"
        "global_load_dwordx2 %9,  %17, off offset:512  sc0 sc1\n\t"
        "global_load_dwordx2 %10, %17, off offset:1024 sc0 sc1\n\t"
        "global_load_dwordx2 %11, %17, off offset:1536 sc0 sc1\n\t"
        "global_load_dwordx2 %12, %17, off offset:2048 sc0 sc1\n\t"
        "global_load_dwordx2 %13, %17, off offset:2560 sc0 sc1\n\t"
        "global_load_dwordx2 %14, %17, off offset:3072 sc0 sc1\n\t"
        "global_load_dwordx2 %15, %17, off offset:3584 sc0 sc1\n\t"
        "s_waitcnt vmcnt(0)"
        : "=&v"(V[0]),  "=&v"(V[1]),  "=&v"(V[2]),  "=&v"(V[3]),
          "=&v"(V[4]),  "=&v"(V[5]),  "=&v"(V[6]),  "=&v"(V[7]),
          "=&v"(V[8]),  "=&v"(V[9]),  "=&v"(V[10]), "=&v"(V[11]),
          "=&v"(V[12]), "=&v"(V[13]), "=&v"(V[14]), "=&v"(V[15])
        : "v"(p0), "v"(p1)
        : "memory");
}

// DPP butterfly add over a 16-lane row (VALU-rate, no LDS pipe).
template <int CTRL>
__device__ __forceinline__ float dpp_xadd(float v) {
    int vi = __float_as_int(v);
    int t  = __builtin_amdgcn_update_dpp(vi, vi, CTRL, 0xF, 0xF, true);
    return v + __int_as_float(t);
}

// fast tanh via v_exp_f32: tanh(x) = sign(x) * (1-e^{-2|x|})/(1+e^{-2|x|}); |err| ~1e-6
__device__ __forceinline__ float fast_tanh(float x) {
    float ax = fabsf(x);
    float e  = __expf(-2.0f * ax);
    float r  = __fdividef(1.0f - e, 1.0f + e);
    return copysignf(r, x);
}

// ================= Kernel 1: xW = x @ W_ih^T + (b_ih + b_hh) =================
__global__ __launch_bounds__(256) void gemm_xw(
    const float* __restrict__ x, const float* __restrict__ Wih,
    const float* __restrict__ bih, const float* __restrict__ bhh,
    float* __restrict__ xW)
{
    __shared__ float As[64][17];
    __shared__ float Bs[64][17];
    const int tid = threadIdx.x;
    const int bx = blockIdx.x;
    const int by = blockIdx.y;
    const int tx = tid & 15;
    const int ty = tid >> 4;
    const int lrow = tid >> 2;
    const int lcol = (tid & 3) * 4;

    const float* Ag = x   + (size_t)(by * 64 + lrow) * E_ + lcol;
    const float* Bg = Wih + (size_t)(bx * 64 + lrow) * E_ + lcol;

    float acc[4][4] = {};
    for (int kt = 0; kt < E_; kt += 16) {
        float4 av = *(const float4*)(Ag + kt);
        float4 bv = *(const float4*)(Bg + kt);
        As[lrow][lcol + 0] = av.x; As[lrow][lcol + 1] = av.y;
        As[lrow][lcol + 2] = av.z; As[lrow][lcol + 3] = av.w;
        Bs[lrow][lcol + 0] = bv.x; Bs[lrow][lcol + 1] = bv.y;
        Bs[lrow][lcol + 2] = bv.z; Bs[lrow][lcol + 3] = bv.w;
        __syncthreads();
#pragma unroll
        for (int kk = 0; kk < 16; ++kk) {
            float a0 = As[ty * 4 + 0][kk], a1 = As[ty * 4 + 1][kk];
            float a2 = As[ty * 4 + 2][kk], a3 = As[ty * 4 + 3][kk];
            float b0 = Bs[tx * 4 + 0][kk], b1 = Bs[tx * 4 + 1][kk];
            float b2 = Bs[tx * 4 + 2][kk], b3 = Bs[tx * 4 + 3][kk];
            acc[0][0] += a0 * b0; acc[0][1] += a0 * b1; acc[0][2] += a0 * b2; acc[0][3] += a0 * b3;
            acc[1][0] += a1 * b0; acc[1][1] += a1 * b1; acc[1][2] += a1 * b2; acc[1][3] += a1 * b3;
            acc[2][0] += a2 * b0; acc[2][1] += a2 * b1; acc[2][2] += a2 * b2; acc[2][3] += a2 * b3;
            acc[3][0] += a3 * b0; acc[3][1] += a3 * b1; acc[3][2] += a3 * b2; acc[3][3] += a3 * b3;
        }
        __syncthreads();
    }
#pragma unroll
    for (int i = 0; i < 4; ++i) {
        const int m = by * 64 + ty * 4 + i;
#pragma unroll
        for (int j = 0; j < 4; ++j) {
            const int n = bx * 64 + tx * 4 + j;
            xW[(size_t)m * H_ + n] = acc[i][j] + bih[n] + bhh[n];
        }
    }
}

// ================= Kernel 2: persistent sequential RNN scan =================
// Tagged-data protocol: slot i of buffer s&1 must carry tag s.
// SINGLE-WAVE POLLER: wave 0 polls all 1024 slots (lane L owns slots L+64k),
// one sampling phase per WG (no cross-wave phase spread), 4x less sc1 traffic.
// Wave 0 stages values into the double-buffered LDS tile; waves 1-3 wait at the
// single per-step barrier. Wave 0 may run ahead into step s+1's poll while
// waves 1-3 finish step s (legal: stage targets buffer cur^1; WAR across steps
// s/s+2 closed by the poll(s+2) -> all-produced(s+2) -> all-read(s) chain).
__global__ __launch_bounds__(256, 1) void rnn_scan(
    const float* __restrict__ Whh, const float* __restrict__ xW,
    const int* __restrict__ lengths,
    u64* __restrict__ hbuf2,   // [2][H_] {tag<<32 | value_bits}
    float* __restrict__ hs)    // [B_][H_]
{
    __shared__ float hsh2[2][16 * 68];
    const int tid = threadIdx.x;
    const int wg  = blockIdx.x;
    const int r   = tid >> 4;     // 0..15
    const int sub = tid & 15;     // 0..15
    const int row = wg * ROWS_PER_WG + r;

    float wreg[64];
#pragma unroll
    for (int j = 0; j < 64; ++j)
        wreg[j] = Whh[(size_t)row * H_ + sub + 16 * j];

    // wave-0 staging address: slot c = tid + 64k -> hsh2[cur][(c&15)*68 + (c>>4)]
    //   = (tid&15)*68 + (tid>>4) + 4k   (each k-write: 2-way banks = free)
    const int stage_base = (tid & 15) * 68 + (tid >> 4);

    int s = 0, cur = 0;
    for (int b = 0; b < B_; ++b) {
        const int len = lengths[b];
        for (int t = 0; t < len; ++t) {
            // xW prefetch (all threads; drains under poll wait / barrier wait)
            float xw = xW[(size_t)(b * T_ + t) * H_ + row];

            if (tid < 64) {
                // ---- wave 0: poll all 1024 tagged slots until every tag == s
                const u64* p0 = hbuf2 + (size_t)(s & 1) * H_ + tid;
                const u64* p1 = p0 + 512;
                const unsigned want = (unsigned)s;
                u64 V[16];
                for (;;) {
                    poll16(p0, p1, V);
                    bool ok = true;
#pragma unroll
                    for (int k = 0; k < 16; ++k)
                        ok &= ((unsigned)(V[k] >> 32) == want);
                    if (__all(ok)) break;
                }
                // ---- stage into current LDS buffer
                float* dst = &hsh2[cur][stage_base];
#pragma unroll
                for (int k = 0; k < 16; ++k)
                    dst[4 * k] = __uint_as_float((unsigned)V[k]);
            }
            __syncthreads();   // the ONLY barrier this step

            // ---- compute: 16x float4 LDS reads, 64 FMA in 4 independent chains
            const float* hrow = &hsh2[cur][sub * 68];
            float p0a = 0.f, p1a = 0.f, p2a = 0.f, p3a = 0.f;
#pragma unroll
            for (int m = 0; m < 16; ++m) {
                float4 hv = *(const float4*)(hrow + 4 * m);
                p0a += wreg[4 * m + 0] * hv.x;
                p1a += wreg[4 * m + 1] * hv.y;
                p2a += wreg[4 * m + 2] * hv.z;
                p3a += wreg[4 * m + 3] * hv.w;
            }
            float p = (p0a + p1a) + (p2a + p3a);
            // DPP butterfly over the 16-lane group (VALU-rate; no LDS pipe)
            p = dpp_xadd<0xB1>(p);    // quad_perm [1,0,3,2]  (xor 1)
            p = dpp_xadd<0x4E>(p);    // quad_perm [2,3,0,1]  (xor 2)
            p = dpp_xadd<0x141>(p);   // row_half_mirror
            p = dpp_xadd<0x140>(p);   // row_mirror

            float v = fast_tanh(xw + p);
            // ---- produce: single tagged 8B device-coherent store (lane sub==0 per row)
            if (sub == 0) {
                u64 pk = ((u64)(unsigned)(s + 1) << 32) | (u64)__float_as_uint(v);
                store_u64_cohere(hbuf2 + (size_t)((s + 1) & 1) * H_ + row, pk);
                if (t == len - 1) hs[(size_t)b * H_ + row] = v;  // final h of this row
            }
            cur ^= 1;
            ++s;
        }
    }
}

// ================= Kernel 3: out = hs @ W_l1^T + b_l1  (16x128) =================
__global__ __launch_bounds__(128) void out_gemm(
    const float* __restrict__ hs, const float* __restrict__ Wl1,
    const float* __restrict__ bl1, float* __restrict__ out)
{
    __shared__ float hshared[H_];
    const int b = blockIdx.x;
    const int d = threadIdx.x;
    for (int i = d; i < H_ / 4; i += 128)
        ((float4*)hshared)[i] = ((const float4*)(hs + (size_t)b * H_))[i];
    __syncthreads();
    float acc = 0.f;
    const float* wrow = Wl1 + (size_t)d * H_;
    for (int h = 0; h < H_; h += 4) {
        float4 w = *(const float4*)(wrow + h);
        acc += w.x * hshared[h] + w.y * hshared[h + 1]
             + w.z * hshared[h + 2] + w.w * hshared[h + 3];
    }
    out[b * D_ + d] = acc + bl1[d];
}

extern "C" void kernel_launch(void* const* d_in, const int* in_sizes, int n_in,
                              void* d_out, int out_size, void* d_ws, size_t ws_size,
                              hipStream_t stream) {
    const float* x       = (const float*)d_in[0];
    const int*   lengths = (const int*)  d_in[1];
    const float* Wih     = (const float*)d_in[2];
    const float* Whh     = (const float*)d_in[3];
    const float* bih     = (const float*)d_in[4];
    const float* bhh     = (const float*)d_in[5];
    const float* Wl1     = (const float*)d_in[6];
    const float* bl1     = (const float*)d_in[7];
    float* out = (float*)d_out;

    char* ws = (char*)d_ws;
    u64*   hbuf2 = (u64*)(ws + 4096);     // 16 KB
    float* hs  = (float*)(ws + 32768);    // 64 KB
    float* xW  = (float*)(ws + 131072);   // 32 MB

    // zero hbuf2 (h0 = 0.0f with tag 0); ws is re-poisoned 0xAA before every launch
    hipMemsetAsync(ws, 0, 32768, stream);

    dim3 g1(H_ / 64, (B_ * T_) / 64);   // (16, 128)
    gemm_xw<<<g1, 256, 0, stream>>>(x, Wih, bih, bhh, xW);

    rnn_scan<<<G_SCAN, 256, 0, stream>>>(Whh, xW, lengths, hbuf2, hs);

    out_gemm<<<B_, D_, 0, stream>>>(hs, Wl1, bl1, out);
}

// Round 7
// 7662.144 us; speedup vs baseline: 1.2565x; 1.2041x over previous
//
#include <hip/hip_runtime.h>
#include <math.h>

#define B_ 16
#define T_ 512
#define E_ 2048
#define H_ 1024
#define D_ 128
#define G_SCAN 64            // persistent workgroups for the scan (1 per CU, 64 <= 256 CUs)
#define ROWS_PER_WG 16       // H_/G_SCAN
#define TICK_P 75            // step period, 100 MHz realtime ticks (0.75 us)
#define START_DELAY 1500     // T0 offset: covers all WGs' wreg loads (~15 us, one-time)
#define T0_MAGIC 0x7F7F7F7Fu

typedef unsigned long long u64;

// ---------------- ws layout ----------------
// [256,   264)   : T0 handshake slot (u64 {magic, t0_low32}) -- zeroed each launch
// [4096,  20480) : hbuf2[2][H_] (u64 {tag,valbits}) -- zeroed each launch (h0=0, tag=0)
// [32768, 98304) : hs[B_][H_] (float)
// [131072,+32MB) : xW[B_*T_][H_] (float)

// ---- device-coherent 8B ops (sc0 sc1: bypass non-coherent caches to coherence point) ----
__device__ __forceinline__ void store_u64_cohere(u64* p, u64 v) {
    asm volatile("global_store_dwordx2 %0, %1, off sc0 sc1"
                 :: "v"(p), "v"(v) : "memory");
}
__device__ __forceinline__ u64 load_u64_cohere(const u64* p) {
    u64 r;
    asm volatile("global_load_dwordx2 %0, %1, off sc0 sc1\n\t"
                 "s_waitcnt vmcnt(0)"
                 : "=v"(r) : "v"(p) : "memory");
    return r;
}
// ---- 4 coherent 8B loads issued back-to-back, ONE waitcnt ----
__device__ __forceinline__ void load4_u64_cohere(
    const u64* p0, const u64* p1, const u64* p2, const u64* p3,
    u64& a, u64& b, u64& c, u64& d) {
    asm volatile("global_load_dwordx2 %0, %4, off sc0 sc1\n\t"
                 "global_load_dwordx2 %1, %5, off sc0 sc1\n\t"
                 "global_load_dwordx2 %2, %6, off sc0 sc1\n\t"
                 "global_load_dwordx2 %3, %7, off sc0 sc1\n\t"
                 "s_waitcnt vmcnt(0)"
                 : "=&v"(a), "=&v"(b), "=&v"(c), "=&v"(d)
                 : "v"(p0), "v"(p1), "v"(p2), "v"(p3)
                 : "memory");
}

// ---- wait until device-global realtime clock (100 MHz, XCD-coherent) reaches target ----
__device__ __forceinline__ void gate_wait(unsigned target) {
    for (;;) {
        unsigned now = (unsigned)__builtin_amdgcn_s_memrealtime();
        if ((int)(now - target) >= 0) break;   // signed diff: wrap-safe
        __builtin_amdgcn_s_sleep(1);
    }
}

// DPP butterfly add over a 16-lane row (VALU-rate, no LDS pipe).
template <int CTRL>
__device__ __forceinline__ float dpp_xadd(float v) {
    int vi = __float_as_int(v);
    int t  = __builtin_amdgcn_update_dpp(vi, vi, CTRL, 0xF, 0xF, true);
    return v + __int_as_float(t);
}

// fast tanh via v_exp_f32: tanh(x) = sign(x) * (1-e^{-2|x|})/(1+e^{-2|x|}); |err| ~1e-6
__device__ __forceinline__ float fast_tanh(float x) {
    float ax = fabsf(x);
    float e  = __expf(-2.0f * ax);
    float r  = __fdividef(1.0f - e, 1.0f + e);
    return copysignf(r, x);
}

// ================= Kernel 1: xW = x @ W_ih^T + (b_ih + b_hh) =================
__global__ __launch_bounds__(256) void gemm_xw(
    const float* __restrict__ x, const float* __restrict__ Wih,
    const float* __restrict__ bih, const float* __restrict__ bhh,
    float* __restrict__ xW)
{
    __shared__ float As[64][17];
    __shared__ float Bs[64][17];
    const int tid = threadIdx.x;
    const int bx = blockIdx.x;
    const int by = blockIdx.y;
    const int tx = tid & 15;
    const int ty = tid >> 4;
    const int lrow = tid >> 2;
    const int lcol = (tid & 3) * 4;

    const float* Ag = x   + (size_t)(by * 64 + lrow) * E_ + lcol;
    const float* Bg = Wih + (size_t)(bx * 64 + lrow) * E_ + lcol;

    float acc[4][4] = {};
    for (int kt = 0; kt < E_; kt += 16) {
        float4 av = *(const float4*)(Ag + kt);
        float4 bv = *(const float4*)(Bg + kt);
        As[lrow][lcol + 0] = av.x; As[lrow][lcol + 1] = av.y;
        As[lrow][lcol + 2] = av.z; As[lrow][lcol + 3] = av.w;
        Bs[lrow][lcol + 0] = bv.x; Bs[lrow][lcol + 1] = bv.y;
        Bs[lrow][lcol + 2] = bv.z; Bs[lrow][lcol + 3] = bv.w;
        __syncthreads();
#pragma unroll
        for (int kk = 0; kk < 16; ++kk) {
            float a0 = As[ty * 4 + 0][kk], a1 = As[ty * 4 + 1][kk];
            float a2 = As[ty * 4 + 2][kk], a3 = As[ty * 4 + 3][kk];
            float b0 = Bs[tx * 4 + 0][kk], b1 = Bs[tx * 4 + 1][kk];
            float b2 = Bs[tx * 4 + 2][kk], b3 = Bs[tx * 4 + 3][kk];
            acc[0][0] += a0 * b0; acc[0][1] += a0 * b1; acc[0][2] += a0 * b2; acc[0][3] += a0 * b3;
            acc[1][0] += a1 * b0; acc[1][1] += a1 * b1; acc[1][2] += a1 * b2; acc[1][3] += a1 * b3;
            acc[2][0] += a2 * b0; acc[2][1] += a2 * b1; acc[2][2] += a2 * b2; acc[2][3] += a2 * b3;
            acc[3][0] += a3 * b0; acc[3][1] += a3 * b1; acc[3][2] += a3 * b2; acc[3][3] += a3 * b3;
        }
        __syncthreads();
    }
#pragma unroll
    for (int i = 0; i < 4; ++i) {
        const int m = by * 64 + ty * 4 + i;
#pragma unroll
        for (int j = 0; j < 4; ++j) {
            const int n = bx * 64 + tx * 4 + j;
            xW[(size_t)m * H_ + n] = acc[i][j] + bih[n] + bhh[n];
        }
    }
}

// ================= Kernel 2: persistent sequential RNN scan =================
// Tagged-data protocol (slot i of buffer s&1 carries tag s) + CLOCK-ALIGNED steps:
// every wave gates step s at absolute realtime T0 + s*TICK_P, so all WGs sample in
// phase and the poll succeeds in one round (tags remain the correctness guarantee;
// a late WG degrades to round-4 polling and re-aligns at the next future gate).
// Thread tid owns slots {tid, tid+256, tid+512, tid+768}. LDS double-buffered,
// ONE barrier per step (WAR safety: poll(s+2) -> all-produced(s+2) -> all-read(s)).
__global__ __launch_bounds__(256, 1) void rnn_scan(
    const float* __restrict__ Whh, const float* __restrict__ xW,
    const int* __restrict__ lengths,
    u64* __restrict__ tsync,   // T0 handshake slot
    u64* __restrict__ hbuf2,   // [2][H_] {tag<<32 | value_bits}
    float* __restrict__ hs)    // [B_][H_]
{
    __shared__ float hsh2[2][16 * 68];
    const int tid = threadIdx.x;
    const int wg  = blockIdx.x;
    const int r   = tid >> 4;     // 0..15
    const int sub = tid & 15;     // 0..15
    const int row = wg * ROWS_PER_WG + r;

    float wreg[64];
#pragma unroll
    for (int j = 0; j < 64; ++j)
        wreg[j] = Whh[(size_t)row * H_ + sub + 16 * j];

    // ---- T0 handshake: WG0 publishes start time; everyone polls for it
    if (wg == 0 && tid == 0) {
        unsigned t0pub = (unsigned)__builtin_amdgcn_s_memrealtime() + START_DELAY;
        store_u64_cohere(tsync, ((u64)T0_MAGIC << 32) | (u64)t0pub);
    }
    unsigned t0;
    {
        u64 v;
        do { v = load_u64_cohere(tsync); } while ((unsigned)(v >> 32) != T0_MAGIC);
        t0 = (unsigned)v;
    }

    int s = 0, cur = 0;
    for (int b = 0; b < B_; ++b) {
        const int len = lengths[b];
        for (int t = 0; t < len; ++t) {
            // xW prefetch: issue before the gate so it flies during the wait
            float xw = xW[(size_t)(b * T_ + t) * H_ + row];

            // ---- clock gate: all WGs start step s at the same instant
            gate_wait(t0 + (unsigned)s * TICK_P);

            // ---- consume: poll 4 tagged slots (normally ONE round after the gate)
            const u64* bin = hbuf2 + (size_t)(s & 1) * H_;
            const unsigned want = (unsigned)s;
            u64 v0, v1, v2, v3;
            for (;;) {
                load4_u64_cohere(bin + tid, bin + tid + 256, bin + tid + 512, bin + tid + 768,
                                 v0, v1, v2, v3);
                if ((((unsigned)(v0 >> 32)) == want) & (((unsigned)(v1 >> 32)) == want) &
                    (((unsigned)(v2 >> 32)) == want) & (((unsigned)(v3 >> 32)) == want))
                    break;
            }

            // stage into current LDS buffer: perm(c)=sub*68 + r + 16k (2-way banks = free)
            float* wr = &hsh2[cur][sub * 68 + r];
            wr[0]  = __uint_as_float((unsigned)v0);
            wr[16] = __uint_as_float((unsigned)v1);
            wr[32] = __uint_as_float((unsigned)v2);
            wr[48] = __uint_as_float((unsigned)v3);
            __syncthreads();   // the ONLY barrier this step

            // ---- compute: 16x float4 LDS reads, 64 FMA in 4 independent chains
            const float* hrow = &hsh2[cur][sub * 68];
            float p0 = 0.f, p1 = 0.f, p2 = 0.f, p3 = 0.f;
#pragma unroll
            for (int m = 0; m < 16; ++m) {
                float4 hv = *(const float4*)(hrow + 4 * m);
                p0 += wreg[4 * m + 0] * hv.x;
                p1 += wreg[4 * m + 1] * hv.y;
                p2 += wreg[4 * m + 2] * hv.z;
                p3 += wreg[4 * m + 3] * hv.w;
            }
            float p = (p0 + p1) + (p2 + p3);
            // DPP butterfly over the 16-lane group (VALU-rate; no LDS pipe)
            p = dpp_xadd<0xB1>(p);    // quad_perm [1,0,3,2]  (xor 1)
            p = dpp_xadd<0x4E>(p);    // quad_perm [2,3,0,1]  (xor 2)
            p = dpp_xadd<0x141>(p);   // row_half_mirror
            p = dpp_xadd<0x140>(p);   // row_mirror

            float v = fast_tanh(xw + p);
            // ---- produce: single tagged 8B device-coherent store (lane sub==0 per row)
            if (sub == 0) {
                u64 pk = ((u64)(unsigned)(s + 1) << 32) | (u64)__float_as_uint(v);
                store_u64_cohere(hbuf2 + (size_t)((s + 1) & 1) * H_ + row, pk);
                if (t == len - 1) hs[(size_t)b * H_ + row] = v;  // final h of this row
            }
            cur ^= 1;
            ++s;
        }
    }
}

// ================= Kernel 3: out = hs @ W_l1^T + b_l1  (16x128) =================
__global__ __launch_bounds__(128) void out_gemm(
    const float* __restrict__ hs, const float* __restrict__ Wl1,
    const float* __restrict__ bl1, float* __restrict__ out)
{
    __shared__ float hshared[H_];
    const int b = blockIdx.x;
    const int d = threadIdx.x;
    for (int i = d; i < H_ / 4; i += 128)
        ((float4*)hshared)[i] = ((const float4*)(hs + (size_t)b * H_))[i];
    __syncthreads();
    float acc = 0.f;
    const float* wrow = Wl1 + (size_t)d * H_;
    for (int h = 0; h < H_; h += 4) {
        float4 w = *(const float4*)(wrow + h);
        acc += w.x * hshared[h] + w.y * hshared[h + 1]
             + w.z * hshared[h + 2] + w.w * hshared[h + 3];
    }
    out[b * D_ + d] = acc + bl1[d];
}

extern "C" void kernel_launch(void* const* d_in, const int* in_sizes, int n_in,
                              void* d_out, int out_size, void* d_ws, size_t ws_size,
                              hipStream_t stream) {
    const float* x       = (const float*)d_in[0];
    const int*   lengths = (const int*)  d_in[1];
    const float* Wih     = (const float*)d_in[2];
    const float* Whh     = (const float*)d_in[3];
    const float* bih     = (const float*)d_in[4];
    const float* bhh     = (const float*)d_in[5];
    const float* Wl1     = (const float*)d_in[6];
    const float* bl1     = (const float*)d_in[7];
    float* out = (float*)d_out;

    char* ws = (char*)d_ws;
    u64*   tsync = (u64*)(ws + 256);      // T0 handshake
    u64*   hbuf2 = (u64*)(ws + 4096);     // 16 KB
    float* hs  = (float*)(ws + 32768);    // 64 KB
    float* xW  = (float*)(ws + 131072);   // 32 MB

    // zero tsync + hbuf2 (h0 = 0.0f with tag 0); ws is re-poisoned 0xAA every launch
    hipMemsetAsync(ws, 0, 32768, stream);

    dim3 g1(H_ / 64, (B_ * T_) / 64);   // (16, 128)
    gemm_xw<<<g1, 256, 0, stream>>>(x, Wih, bih, bhh, xW);

    rnn_scan<<<G_SCAN, 256, 0, stream>>>(Whh, xW, lengths, tsync, hbuf2, hs);

    out_gemm<<<B_, D_, 0, stream>>>(hs, Wl1, bl1, out);
}

// Round 8
// 7529.898 us; speedup vs baseline: 1.2786x; 1.0176x over previous
//
#include <hip/hip_runtime.h>
#include <math.h>

#define B_ 16
#define T_ 512
#define E_ 2048
#define H_ 1024
#define D_ 128
#define G_SCAN 64            // persistent workgroups for the scan (1 per CU, 64 <= 256 CUs)
#define ROWS_PER_WG 16       // H_/G_SCAN
#define TICK_P 100           // step period, 100 MHz realtime ticks (1.0 us)
#define EPOCH_L 16           // steps per epoch (re-anchor interval)
#define ANCHOR_S 80          // anchor slack, ticks
#define START_DELAY 1500     // T0 offset: covers wreg loads + launch skew (one-time)
#define T0_MAGIC 0x7F7F7F7Fu

typedef unsigned long long u64;

// ---------------- ws layout ----------------
// [256,  264)    : T0 handshake slot (u64 {magic, t0_low32}) -- zeroed each launch
// [512,  544)    : anchor ring u64[4], tag = epoch index (>=1)  -- zeroed each launch
// [4096, 20480)  : hbuf2[2][H_] (u64 {tag,valbits}) -- zeroed each launch (h0=0, tag=0)
// [32768,98304)  : hs[B_][H_] (float)
// [131072,+32MB) : xW[B_*T_][H_] (float)

// ---- device-coherent 8B ops (sc0 sc1: bypass non-coherent caches to coherence point) ----
__device__ __forceinline__ void store_u64_cohere(u64* p, u64 v) {
    asm volatile("global_store_dwordx2 %0, %1, off sc0 sc1"
                 :: "v"(p), "v"(v) : "memory");
}
__device__ __forceinline__ u64 load_u64_cohere(const u64* p) {
    u64 r;
    asm volatile("global_load_dwordx2 %0, %1, off sc0 sc1\n\t"
                 "s_waitcnt vmcnt(0)"
                 : "=v"(r) : "v"(p) : "memory");
    return r;
}
// ---- 4 coherent 8B loads issued back-to-back, ONE waitcnt ----
__device__ __forceinline__ void load4_u64_cohere(
    const u64* p0, const u64* p1, const u64* p2, const u64* p3,
    u64& a, u64& b, u64& c, u64& d) {
    asm volatile("global_load_dwordx2 %0, %4, off sc0 sc1\n\t"
                 "global_load_dwordx2 %1, %5, off sc0 sc1\n\t"
                 "global_load_dwordx2 %2, %6, off sc0 sc1\n\t"
                 "global_load_dwordx2 %3, %7, off sc0 sc1\n\t"
                 "s_waitcnt vmcnt(0)"
                 : "=&v"(a), "=&v"(b), "=&v"(c), "=&v"(d)
                 : "v"(p0), "v"(p1), "v"(p2), "v"(p3)
                 : "memory");
}

// ---- wait until device-global realtime clock (100 MHz, XCD-coherent) reaches target ----
__device__ __forceinline__ void gate_wait(unsigned target) {
    for (;;) {
        unsigned now = (unsigned)__builtin_amdgcn_s_memrealtime();
        if ((int)(now - target) >= 0) break;   // signed diff: wrap-safe
        __builtin_amdgcn_s_sleep(1);
    }
}

// DPP butterfly add over a 16-lane row (VALU-rate, no LDS pipe).
template <int CTRL>
__device__ __forceinline__ float dpp_xadd(float v) {
    int vi = __float_as_int(v);
    int t  = __builtin_amdgcn_update_dpp(vi, vi, CTRL, 0xF, 0xF, true);
    return v + __int_as_float(t);
}

// fast tanh via v_exp_f32: tanh(x) = sign(x) * (1-e^{-2|x|})/(1+e^{-2|x|}); |err| ~1e-6
__device__ __forceinline__ float fast_tanh(float x) {
    float ax = fabsf(x);
    float e  = __expf(-2.0f * ax);
    float r  = __fdividef(1.0f - e, 1.0f + e);
    return copysignf(r, x);
}

// ================= Kernel 1: xW = x @ W_ih^T + (b_ih + b_hh) =================
__global__ __launch_bounds__(256) void gemm_xw(
    const float* __restrict__ x, const float* __restrict__ Wih,
    const float* __restrict__ bih, const float* __restrict__ bhh,
    float* __restrict__ xW)
{
    __shared__ float As[64][17];
    __shared__ float Bs[64][17];
    const int tid = threadIdx.x;
    const int bx = blockIdx.x;
    const int by = blockIdx.y;
    const int tx = tid & 15;
    const int ty = tid >> 4;
    const int lrow = tid >> 2;
    const int lcol = (tid & 3) * 4;

    const float* Ag = x   + (size_t)(by * 64 + lrow) * E_ + lcol;
    const float* Bg = Wih + (size_t)(bx * 64 + lrow) * E_ + lcol;

    float acc[4][4] = {};
    for (int kt = 0; kt < E_; kt += 16) {
        float4 av = *(const float4*)(Ag + kt);
        float4 bv = *(const float4*)(Bg + kt);
        As[lrow][lcol + 0] = av.x; As[lrow][lcol + 1] = av.y;
        As[lrow][lcol + 2] = av.z; As[lrow][lcol + 3] = av.w;
        Bs[lrow][lcol + 0] = bv.x; Bs[lrow][lcol + 1] = bv.y;
        Bs[lrow][lcol + 2] = bv.z; Bs[lrow][lcol + 3] = bv.w;
        __syncthreads();
#pragma unroll
        for (int kk = 0; kk < 16; ++kk) {
            float a0 = As[ty * 4 + 0][kk], a1 = As[ty * 4 + 1][kk];
            float a2 = As[ty * 4 + 2][kk], a3 = As[ty * 4 + 3][kk];
            float b0 = Bs[tx * 4 + 0][kk], b1 = Bs[tx * 4 + 1][kk];
            float b2 = Bs[tx * 4 + 2][kk], b3 = Bs[tx * 4 + 3][kk];
            acc[0][0] += a0 * b0; acc[0][1] += a0 * b1; acc[0][2] += a0 * b2; acc[0][3] += a0 * b3;
            acc[1][0] += a1 * b0; acc[1][1] += a1 * b1; acc[1][2] += a1 * b2; acc[1][3] += a1 * b3;
            acc[2][0] += a2 * b0; acc[2][1] += a2 * b1; acc[2][2] += a2 * b2; acc[2][3] += a2 * b3;
            acc[3][0] += a3 * b0; acc[3][1] += a3 * b1; acc[3][2] += a3 * b2; acc[3][3] += a3 * b3;
        }
        __syncthreads();
    }
#pragma unroll
    for (int i = 0; i < 4; ++i) {
        const int m = by * 64 + ty * 4 + i;
#pragma unroll
        for (int j = 0; j < 4; ++j) {
            const int n = bx * 64 + tx * 4 + j;
            xW[(size_t)m * H_ + n] = acc[i][j] + bih[n] + bhh[n];
        }
    }
}

// ================= Kernel 2: persistent sequential RNN scan =================
// Tagged-data protocol (slot i of buffer s&1 carries tag s) + EPOCH-RE-ANCHORED
// clock gating: every EPOCH_L steps WG0 publishes a fresh anchor A_e = now+S via
// a tagged ring slot; all WGs gate step s at A_e + (s mod L)*P. A transient slip
// de-gates at most the rest of one epoch (free-run = round-4 behavior), then
// re-aligns. Tags remain the sole correctness mechanism.
__global__ __launch_bounds__(256, 1) void rnn_scan(
    const float* __restrict__ Whh, const float* __restrict__ xW,
    const int* __restrict__ lengths,
    u64* __restrict__ tsync,    // T0 handshake slot
    u64* __restrict__ anchors,  // ring of 4 tagged anchor slots
    u64* __restrict__ hbuf2,    // [2][H_] {tag<<32 | value_bits}
    float* __restrict__ hs)     // [B_][H_]
{
    __shared__ float hsh2[2][16 * 68];
    __shared__ unsigned sh_anchor;
    const int tid = threadIdx.x;
    const int wg  = blockIdx.x;
    const int r   = tid >> 4;     // 0..15
    const int sub = tid & 15;     // 0..15
    const int row = wg * ROWS_PER_WG + r;

    float wreg[64];
#pragma unroll
    for (int j = 0; j < 64; ++j)
        wreg[j] = Whh[(size_t)row * H_ + sub + 16 * j];

    // ---- T0 handshake: WG0 publishes epoch-0 anchor; everyone polls for it
    if (wg == 0 && tid == 0) {
        unsigned t0pub = (unsigned)__builtin_amdgcn_s_memrealtime() + START_DELAY;
        store_u64_cohere(tsync, ((u64)T0_MAGIC << 32) | (u64)t0pub);
    }
    unsigned anchor;
    {
        u64 v;
        do { v = load_u64_cohere(tsync); } while ((unsigned)(v >> 32) != T0_MAGIC);
        anchor = (unsigned)v;
    }

    int s = 0, cur = 0;
    for (int b = 0; b < B_; ++b) {
        const int len = lengths[b];
        for (int t = 0; t < len; ++t) {
            // xW prefetch: issue before the gate so it flies during the wait
            float xw = xW[(size_t)(b * T_ + t) * H_ + row];

            // ---- epoch boundary: refresh anchor (epoch e = s/L, ring slot e&3)
            const int ep = s >> 4;                 // EPOCH_L = 16
            if ((s & (EPOCH_L - 1)) == 0 && ep >= 1) {
                u64* slot = anchors + (ep & 3);
                if (wg == 0) {
                    if (tid == 0) {
                        unsigned a = (unsigned)__builtin_amdgcn_s_memrealtime() + ANCHOR_S;
                        store_u64_cohere(slot, ((u64)(unsigned)ep << 32) | (u64)a);
                        sh_anchor = a;
                    }
                } else {
                    if (tid == 0) {
                        u64 v;
                        do { v = load_u64_cohere(slot); } while ((unsigned)(v >> 32) != (unsigned)ep);
                        sh_anchor = (unsigned)v;
                    }
                }
                __syncthreads();
                anchor = sh_anchor;
            }

            // ---- clock gate: all WGs start step s at the same instant
            gate_wait(anchor + (unsigned)(s & (EPOCH_L - 1)) * TICK_P);

            // ---- consume: poll 4 tagged slots (normally ONE round after the gate)
            const u64* bin = hbuf2 + (size_t)(s & 1) * H_;
            const unsigned want = (unsigned)s;
            u64 v0, v1, v2, v3;
            for (;;) {
                load4_u64_cohere(bin + tid, bin + tid + 256, bin + tid + 512, bin + tid + 768,
                                 v0, v1, v2, v3);
                if ((((unsigned)(v0 >> 32)) == want) & (((unsigned)(v1 >> 32)) == want) &
                    (((unsigned)(v2 >> 32)) == want) & (((unsigned)(v3 >> 32)) == want))
                    break;
            }

            // stage into current LDS buffer: perm(c)=sub*68 + r + 16k (2-way banks = free)
            float* wr = &hsh2[cur][sub * 68 + r];
            wr[0]  = __uint_as_float((unsigned)v0);
            wr[16] = __uint_as_float((unsigned)v1);
            wr[32] = __uint_as_float((unsigned)v2);
            wr[48] = __uint_as_float((unsigned)v3);
            __syncthreads();   // the per-step barrier

            // ---- compute: 16x float4 LDS reads, 64 FMA in 4 independent chains
            const float* hrow = &hsh2[cur][sub * 68];
            float p0 = 0.f, p1 = 0.f, p2 = 0.f, p3 = 0.f;
#pragma unroll
            for (int m = 0; m < 16; ++m) {
                float4 hv = *(const float4*)(hrow + 4 * m);
                p0 += wreg[4 * m + 0] * hv.x;
                p1 += wreg[4 * m + 1] * hv.y;
                p2 += wreg[4 * m + 2] * hv.z;
                p3 += wreg[4 * m + 3] * hv.w;
            }
            float p = (p0 + p1) + (p2 + p3);
            // DPP butterfly over the 16-lane group (VALU-rate; no LDS pipe)
            p = dpp_xadd<0xB1>(p);    // quad_perm [1,0,3,2]  (xor 1)
            p = dpp_xadd<0x4E>(p);    // quad_perm [2,3,0,1]  (xor 2)
            p = dpp_xadd<0x141>(p);   // row_half_mirror
            p = dpp_xadd<0x140>(p);   // row_mirror

            float v = fast_tanh(xw + p);
            // ---- produce: single tagged 8B device-coherent store (lane sub==0 per row)
            if (sub == 0) {
                u64 pk = ((u64)(unsigned)(s + 1) << 32) | (u64)__float_as_uint(v);
                store_u64_cohere(hbuf2 + (size_t)((s + 1) & 1) * H_ + row, pk);
                if (t == len - 1) hs[(size_t)b * H_ + row] = v;  // final h of this row
            }
            cur ^= 1;
            ++s;
        }
    }
}

// ================= Kernel 3: out = hs @ W_l1^T + b_l1  (16x128) =================
__global__ __launch_bounds__(128) void out_gemm(
    const float* __restrict__ hs, const float* __restrict__ Wl1,
    const float* __restrict__ bl1, float* __restrict__ out)
{
    __shared__ float hshared[H_];
    const int b = blockIdx.x;
    const int d = threadIdx.x;
    for (int i = d; i < H_ / 4; i += 128)
        ((float4*)hshared)[i] = ((const float4*)(hs + (size_t)b * H_))[i];
    __syncthreads();
    float acc = 0.f;
    const float* wrow = Wl1 + (size_t)d * H_;
    for (int h = 0; h < H_; h += 4) {
        float4 w = *(const float4*)(wrow + h);
        acc += w.x * hshared[h] + w.y * hshared[h + 1]
             + w.z * hshared[h + 2] + w.w * hshared[h + 3];
    }
    out[b * D_ + d] = acc + bl1[d];
}

extern "C" void kernel_launch(void* const* d_in, const int* in_sizes, int n_in,
                              void* d_out, int out_size, void* d_ws, size_t ws_size,
                              hipStream_t stream) {
    const float* x       = (const float*)d_in[0];
    const int*   lengths = (const int*)  d_in[1];
    const float* Wih     = (const float*)d_in[2];
    const float* Whh     = (const float*)d_in[3];
    const float* bih     = (const float*)d_in[4];
    const float* bhh     = (const float*)d_in[5];
    const float* Wl1     = (const float*)d_in[6];
    const float* bl1     = (const float*)d_in[7];
    float* out = (float*)d_out;

    char* ws = (char*)d_ws;
    u64*   tsync   = (u64*)(ws + 256);    // T0 handshake
    u64*   anchors = (u64*)(ws + 512);    // anchor ring (4 slots)
    u64*   hbuf2   = (u64*)(ws + 4096);   // 16 KB
    float* hs  = (float*)(ws + 32768);    // 64 KB
    float* xW  = (float*)(ws + 131072);   // 32 MB

    // zero tsync + anchors + hbuf2; ws is re-poisoned 0xAA before every launch
    hipMemsetAsync(ws, 0, 32768, stream);

    dim3 g1(H_ / 64, (B_ * T_) / 64);   // (16, 128)
    gemm_xw<<<g1, 256, 0, stream>>>(x, Wih, bih, bhh, xW);

    rnn_scan<<<G_SCAN, 256, 0, stream>>>(Whh, xW, lengths, tsync, anchors, hbuf2, hs);

    out_gemm<<<B_, D_, 0, stream>>>(hs, Wl1, bl1, out);
}